// Round 4
// baseline (137.944 us; speedup 1.0000x reference)
//
#include <hip/hip_runtime.h>
#include <math.h>

#define A_N   8732
#define C_N   81
#define B_N   32
#define NCLS  80
#define NTASK (B_N * NCLS)
#define GRIDM 1280            // persistent blocks; each handles exactly 2 tasks
#define TOPK  100
#define NTHR  256
#define BINS  2048
#define SH    21              // 32 - 11 bits -> 2048 bins
#define CAND  320
#define TA    64

// ln(3/7) in f64: sigmoid_f64(x) > 0.3  <=>  x > THR_LOGIT
#define THR_LOGIT (-0.8472978603872034)

// Monotone map: float bits -> unsigned, order-preserving. 0 = invalid sentinel.
__device__ __forceinline__ unsigned mapf(float x) {
    unsigned b = __float_as_uint(x);
    return b ^ ((b & 0x80000000u) ? 0xFFFFFFFFu : 0x80000000u);
}
__device__ __forceinline__ float unmapf(unsigned u) {
    unsigned b = (u & 0x80000000u) ? (u ^ 0x80000000u) : ~u;
    return __uint_as_float(b);
}

// ---- Kernel T: coalesced logits read, keys transposed to (B, 80, A) ----
__global__ __launch_bounds__(NTHR) void key_transpose_kernel(
    const float* __restrict__ logits,    // (B, A, 81)
    unsigned* __restrict__ keys)         // (B, 80, A)
{
    __shared__ unsigned tile[NCLS][TA + 1];   // 80 x 65 words = 20.8 KB
    const int NT = (A_N + TA - 1) / TA;       // 137
    const int b  = blockIdx.x / NT;
    const int t0 = blockIdx.x % NT;
    const int a0 = t0 * TA;
    const int an = min(TA, A_N - a0);
    const int tid = threadIdx.x;

    const float* src = logits + ((size_t)b * A_N + a0) * C_N;

    if (an == TA) {
        const float4* src4 = (const float4*)src;
        const int total4 = TA * C_N / 4;      // 1296
        for (int i = tid; i < total4; i += NTHR) {
            float4 v = src4[i];
            int base = 4 * i;
            int r  = base / C_N;
            int ch = base - r * C_N;
            float xs[4] = { v.x, v.y, v.z, v.w };
            #pragma unroll
            for (int k = 0; k < 4; ++k) {
                if (ch > 0)
                    tile[ch - 1][r] = ((double)xs[k] > THR_LOGIT) ? mapf(xs[k]) : 0u;
                if (++ch == C_N) { ch = 0; ++r; }
            }
        }
        __syncthreads();
        const int R4 = TA / 4;                // 16 uint4 per class row
        for (int i = tid; i < NCLS * R4; i += NTHR) {
            int row = i >> 4, j = i & (R4 - 1);
            uint4 w;
            w.x = tile[row][4 * j + 0];
            w.y = tile[row][4 * j + 1];
            w.z = tile[row][4 * j + 2];
            w.w = tile[row][4 * j + 3];
            *(uint4*)(keys + ((size_t)b * NCLS + row) * A_N + a0 + 4 * j) = w;
        }
    } else {
        const int total = an * C_N;
        for (int i = tid; i < total; i += NTHR) {
            int r = i / C_N, ch = i - r * C_N;
            float x = src[i];
            if (ch > 0)
                tile[ch - 1][r] = ((double)x > THR_LOGIT) ? mapf(x) : 0u;
        }
        __syncthreads();
        for (int i = tid; i < NCLS * an; i += NTHR) {
            int row = i / an, col = i - row * an;
            keys[((size_t)b * NCLS + row) * A_N + a0 + col] = tile[row][col];
        }
    }
}

// ---- Kernel M: persistent blocks, 2 tasks each: top-100 select + decode + NMS ----
template<bool USE_WS>
__global__ __launch_bounds__(NTHR) void ssd_nms_kernel(
    const float* __restrict__ logits,
    const unsigned* __restrict__ keys,
    const float* __restrict__ boxreg,
    const float* __restrict__ priors,
    float* __restrict__ out)
{
    const int tid = threadIdx.x;

    __shared__ unsigned hist[BINS];               // 8 KB
    __shared__ unsigned bsum[NTHR];
    __shared__ unsigned long long cand[CAND];
    __shared__ unsigned long long ssel[TOPK];
    __shared__ double sb0[TOPK], sb1[TOPK], sb2[TOPK], sb3[TOPK];
    __shared__ double sarea[TOPK], sscore[TOPK];
    __shared__ int svalid[TOPK];
    __shared__ unsigned long long supmask[TOPK][2];
    __shared__ unsigned long long keepw[2];
    __shared__ int scal[2];

    for (int task = blockIdx.x; task < NTASK; task += GRIDM) {
        const int b = task / NCLS;
        const int c = task % NCLS;

        const unsigned* krow = USE_WS ? (keys + ((size_t)b * NCLS + c) * A_N)
                                      : (const unsigned*)0;
        const float* lg = logits + ((size_t)b * A_N * C_N) + (c + 1);

        // ---- init (previous task fully consumed; barrier at loop end)
        for (int k = tid; k < BINS; k += NTHR) hist[k] = 0;
        for (int i = tid; i < CAND; i += NTHR) cand[i] = 0ull;
        if (tid < TOPK) ssel[tid] = 0ull;
        if (tid == 0) { scal[0] = 0; scal[1] = 1; }
        __syncthreads();

        // ---- Pass A: 2048-bin histogram of valid keys
        if (USE_WS) {
            const uint4* src = (const uint4*)krow;
            for (int i = tid; i < A_N / 4; i += NTHR) {
                uint4 v = src[i];
                if (v.x) atomicAdd(&hist[v.x >> SH], 1u);
                if (v.y) atomicAdd(&hist[v.y >> SH], 1u);
                if (v.z) atomicAdd(&hist[v.z >> SH], 1u);
                if (v.w) atomicAdd(&hist[v.w >> SH], 1u);
            }
        } else {
            for (int a = tid; a < A_N; a += NTHR) {
                float x = lg[(size_t)a * C_N];
                if ((double)x > THR_LOGIT) atomicAdd(&hist[mapf(x) >> SH], 1u);
            }
        }
        __syncthreads();

        // ---- parallel suffix scan to locate the 100th-largest key's bin
        {
            unsigned s = 0;
            #pragma unroll
            for (int k = 0; k < BINS / NTHR; ++k) s += hist[tid * (BINS / NTHR) + k];
            bsum[tid] = s;
        }
        __syncthreads();
        for (int off = 1; off < NTHR; off <<= 1) {
            unsigned v = (tid + off < NTHR) ? bsum[tid + off] : 0u;
            __syncthreads();
            bsum[tid] += v;
            __syncthreads();
        }
        {
            unsigned mine = bsum[tid];
            unsigned nxt = (tid < NTHR - 1) ? bsum[tid + 1] : 0u;
            if (mine >= TOPK && nxt < TOPK) {
                unsigned running = nxt;
                #pragma unroll
                for (int k = BINS / NTHR - 1; k >= 0; --k) {
                    running += hist[tid * (BINS / NTHR) + k];
                    if (running >= TOPK) {
                        scal[1] = (int)(((unsigned)(tid * (BINS / NTHR) + k)) << SH);
                        break;
                    }
                }
            }
        }
        __syncthreads();
        const unsigned cutoff = (unsigned)scal[1];

        // ---- Pass B: gather candidates >= cutoff (superset of top-100, L3-hit)
        if (USE_WS) {
            const uint4* src = (const uint4*)krow;
            for (int i = tid; i < A_N / 4; i += NTHR) {
                uint4 v = src[i];
                int a4 = 4 * i;
                if (v.x >= cutoff) {
                    int p = atomicAdd(&scal[0], 1);
                    if (p < CAND) cand[p] = ((unsigned long long)v.x << 32) | (unsigned)(~(unsigned)(a4 + 0));
                }
                if (v.y >= cutoff) {
                    int p = atomicAdd(&scal[0], 1);
                    if (p < CAND) cand[p] = ((unsigned long long)v.y << 32) | (unsigned)(~(unsigned)(a4 + 1));
                }
                if (v.z >= cutoff) {
                    int p = atomicAdd(&scal[0], 1);
                    if (p < CAND) cand[p] = ((unsigned long long)v.z << 32) | (unsigned)(~(unsigned)(a4 + 2));
                }
                if (v.w >= cutoff) {
                    int p = atomicAdd(&scal[0], 1);
                    if (p < CAND) cand[p] = ((unsigned long long)v.w << 32) | (unsigned)(~(unsigned)(a4 + 3));
                }
            }
        } else {
            for (int a = tid; a < A_N; a += NTHR) {
                float x = lg[(size_t)a * C_N];
                if ((double)x > THR_LOGIT) {
                    unsigned u = mapf(x);
                    if (u >= cutoff) {
                        int p = atomicAdd(&scal[0], 1);
                        if (p < CAND) cand[p] = ((unsigned long long)u << 32) | (unsigned)(~(unsigned)a);
                    }
                }
            }
        }
        __syncthreads();

        // ---- exact rank via all-pairs over the M gathered (bounded, balanced)
        {
            int M = scal[0]; if (M > CAND) M = CAND;
            int Mr = (M + 7) & ~7;                 // round up for unroll
            for (int i = tid; i < Mr; i += NTHR) {
                unsigned long long mykey = cand[i];
                int rank = 0;
                #pragma unroll 8
                for (int j = 0; j < Mr; ++j) rank += (cand[j] > mykey) ? 1 : 0;
                if (mykey != 0ull && rank < TOPK) ssel[rank] = mykey;
            }
        }
        __syncthreads();

        // ---- decode top-100 boxes in f64 (reference op order)
        if (tid < TOPK) {
            unsigned long long key = ssel[tid];
            int valid = (key != 0ull);
            double b0 = 0, b1 = 0, b2 = 0, b3 = 0, area = 0, sc = 0;
            if (valid) {
                int a = (int)(~(unsigned)key);
                float x = unmapf((unsigned)(key >> 32));
                sc = 1.0 / (1.0 + exp(-(double)x));
                float4 r4 = *(const float4*)(boxreg + ((size_t)b * A_N + a) * 4);
                float4 p4 = *(const float4*)(priors + (size_t)a * 4);
                double ty = (double)r4.x / 10.0;
                double tx = (double)r4.y / 10.0;
                double th = (double)r4.z / 5.0;
                double tw = (double)r4.w / 5.0;
                double py = (double)p4.x, px = (double)p4.y;
                double ph = (double)p4.z, pw = (double)p4.w;
                double cy = ty * ph + py;
                double cx = tx * pw + px;
                double hh = exp(th) * ph;
                double ww = exp(tw) * pw;
                b0 = cy - hh / 2.0; b1 = cx - ww / 2.0;
                b2 = cy + hh / 2.0; b3 = cx + ww / 2.0;
                double e0 = b2 - b0; if (e0 < 0.0) e0 = 0.0;
                double e1 = b3 - b1; if (e1 < 0.0) e1 = 0.0;
                area = e0 * e1;
            }
            sb0[tid] = b0; sb1[tid] = b1; sb2[tid] = b2; sb3[tid] = b3;
            sarea[tid] = area; sscore[tid] = sc;
            svalid[tid] = valid;
        }
        __syncthreads();

        // ---- suppression bitmask: thread t -> row i = t>>1, word w = t&1
        if (tid < 2 * TOPK) {
            int i = tid >> 1, w = tid & 1;
            unsigned long long m = 0;
            if (svalid[i]) {
                double i0 = sb0[i], i1 = sb1[i], i2 = sb2[i], i3 = sb3[i], ia = sarea[i];
                int jbase = w * 64;
                int jend = min(jbase + 64, TOPK);
                int jstart = (jbase > i + 1) ? jbase : (i + 1);
                for (int j = jstart; j < jend; ++j) {
                    double tl0 = fmax(i0, sb0[j]);
                    double tl1 = fmax(i1, sb1[j]);
                    double br0 = fmin(i2, sb2[j]);
                    double br1 = fmin(i3, sb3[j]);
                    double wh0 = br0 - tl0; if (wh0 < 0.0) wh0 = 0.0;
                    double wh1 = br1 - tl1; if (wh1 < 0.0) wh1 = 0.0;
                    double inter = wh0 * wh1;
                    double iou = inter / (((ia + sarea[j]) - inter) + 1e-9);
                    if (iou > 0.6) m |= 1ull << (j - jbase);
                }
            }
            supmask[i][w] = m;
        }
        __syncthreads();

        // ---- serial greedy scan over bitmasks
        if (tid == 0) {
            unsigned long long kp0 = ~0ull, kp1 = ~0ull;
            for (int i = 0; i < TOPK; ++i) {
                bool kb = (i < 64) ? ((kp0 >> i) & 1ull) : ((kp1 >> (i - 64)) & 1ull);
                if (kb && svalid[i]) { kp0 &= ~supmask[i][0]; kp1 &= ~supmask[i][1]; }
            }
            keepw[0] = kp0; keepw[1] = kp1;
        }
        __syncthreads();

        // ---- write 5 floats per slot
        if (tid < TOPK) {
            bool kb = (tid < 64) ? ((keepw[0] >> tid) & 1ull)
                                 : ((keepw[1] >> (tid - 64)) & 1ull);
            bool kp = kb && (svalid[tid] != 0);
            size_t base = ((size_t)task * TOPK + tid) * 5;
            out[base + 0] = kp ? (float)sb0[tid] : 0.0f;
            out[base + 1] = kp ? (float)sb1[tid] : 0.0f;
            out[base + 2] = kp ? (float)sb2[tid] : 0.0f;
            out[base + 3] = kp ? (float)sb3[tid] : 0.0f;
            out[base + 4] = kp ? (float)sscore[tid] : 0.0f;
        }
        __syncthreads();   // LDS fully consumed before next task's init
    }
}

extern "C" void kernel_launch(void* const* d_in, const int* in_sizes, int n_in,
                              void* d_out, int out_size, void* d_ws, size_t ws_size,
                              hipStream_t stream) {
    const float* logits = (const float*)d_in[0];
    const float* boxreg = (const float*)d_in[1];
    const float* priors = (const float*)d_in[2];
    float* out = (float*)d_out;

    const size_t need = (size_t)B_N * NCLS * A_N * sizeof(unsigned);  // 89.4 MB
    if (ws_size >= need) {
        unsigned* keysw = (unsigned*)d_ws;
        const int NT = (A_N + TA - 1) / TA;
        key_transpose_kernel<<<dim3(B_N * NT), dim3(NTHR), 0, stream>>>(logits, keysw);
        ssd_nms_kernel<true><<<dim3(GRIDM), dim3(NTHR), 0, stream>>>(
            logits, keysw, boxreg, priors, out);
    } else {
        ssd_nms_kernel<false><<<dim3(GRIDM), dim3(NTHR), 0, stream>>>(
            logits, nullptr, boxreg, priors, out);
    }
}

// Round 5
// 112.960 us; speedup vs baseline: 1.2212x; 1.2212x over previous
//
#include <hip/hip_runtime.h>
#include <math.h>

#define A_N   8732
#define C_N   81
#define B_N   32
#define NCLS  80
#define NTASK (B_N * NCLS)
#define TOPK  100
#define NTHR  256
#define BINS  2048
#define SH    21              // 32 - 11 bits -> 2048 bins
#define CAND  320
#define TA    64
#define NV4   2183            // A_N / 4
#define KPT   9               // ceil(NV4 / NTHR) uint4 per thread

// ln(3/7) in f64: sigmoid_f64(x) > 0.3  <=>  x > THR_LOGIT
#define THR_LOGIT (-0.8472978603872034)

// Monotone map: float bits -> unsigned, order-preserving. 0 = invalid sentinel.
__device__ __forceinline__ unsigned mapf(float x) {
    unsigned b = __float_as_uint(x);
    return b ^ ((b & 0x80000000u) ? 0xFFFFFFFFu : 0x80000000u);
}
__device__ __forceinline__ float unmapf(unsigned u) {
    unsigned b = (u & 0x80000000u) ? (u ^ 0x80000000u) : ~u;
    return __uint_as_float(b);
}

// ---- Kernel T: coalesced logits read, keys transposed to (B, 80, A) ----
__global__ __launch_bounds__(NTHR) void key_transpose_kernel(
    const float* __restrict__ logits,    // (B, A, 81)
    unsigned* __restrict__ keys)         // (B, 80, A)
{
    __shared__ unsigned tile[NCLS][TA + 1];   // 80 x 65 words = 20.8 KB
    const int NT = (A_N + TA - 1) / TA;       // 137
    const int b  = blockIdx.x / NT;
    const int t0 = blockIdx.x % NT;
    const int a0 = t0 * TA;
    const int an = min(TA, A_N - a0);
    const int tid = threadIdx.x;

    const float* src = logits + ((size_t)b * A_N + a0) * C_N;

    if (an == TA) {
        const float4* src4 = (const float4*)src;
        const int total4 = TA * C_N / 4;      // 1296
        for (int i = tid; i < total4; i += NTHR) {
            float4 v = src4[i];
            int base = 4 * i;
            int r  = base / C_N;
            int ch = base - r * C_N;
            float xs[4] = { v.x, v.y, v.z, v.w };
            #pragma unroll
            for (int k = 0; k < 4; ++k) {
                if (ch > 0)
                    tile[ch - 1][r] = ((double)xs[k] > THR_LOGIT) ? mapf(xs[k]) : 0u;
                if (++ch == C_N) { ch = 0; ++r; }
            }
        }
        __syncthreads();
        const int R4 = TA / 4;                // 16 uint4 per class row
        for (int i = tid; i < NCLS * R4; i += NTHR) {
            int row = i >> 4, j = i & (R4 - 1);
            uint4 w;
            w.x = tile[row][4 * j + 0];
            w.y = tile[row][4 * j + 1];
            w.z = tile[row][4 * j + 2];
            w.w = tile[row][4 * j + 3];
            *(uint4*)(keys + ((size_t)b * NCLS + row) * A_N + a0 + 4 * j) = w;
        }
    } else {
        const int total = an * C_N;
        for (int i = tid; i < total; i += NTHR) {
            int r = i / C_N, ch = i - r * C_N;
            float x = src[i];
            if (ch > 0)
                tile[ch - 1][r] = ((double)x > THR_LOGIT) ? mapf(x) : 0u;
        }
        __syncthreads();
        for (int i = tid; i < NCLS * an; i += NTHR) {
            int row = i / an, col = i - row * an;
            keys[((size_t)b * NCLS + row) * A_N + a0 + col] = tile[row][col];
        }
    }
}

// ---- Kernel M: one task per block; register-staged keys, single global pass ----
template<bool USE_WS>
__global__ __launch_bounds__(NTHR) void ssd_nms_kernel(
    const float* __restrict__ logits,
    const unsigned* __restrict__ keys,
    const float* __restrict__ boxreg,
    const float* __restrict__ priors,
    float* __restrict__ out)
{
    const int task = blockIdx.x;
    const int b = task / NCLS;
    const int c = task % NCLS;
    const int tid = threadIdx.x;

    __shared__ unsigned hist[BINS];               // 8 KB
    __shared__ unsigned wtot[4];
    __shared__ unsigned long long cand[CAND];
    __shared__ unsigned long long ssel[TOPK];
    __shared__ double sb0[TOPK], sb1[TOPK], sb2[TOPK], sb3[TOPK];
    __shared__ double sarea[TOPK], sscore[TOPK];
    __shared__ int svalid[TOPK];
    __shared__ unsigned long long supmask[TOPK][2];
    __shared__ unsigned long long keepw[2];
    __shared__ int scal[2];

    // ---- issue ALL key loads up front (independent, deep in-flight queue)
    uint4 kreg[KPT];
    if (USE_WS) {
        const uint4* src = (const uint4*)(keys + ((size_t)b * NCLS + c) * A_N);
        #pragma unroll
        for (int j = 0; j < KPT; ++j) {
            int i = tid + j * NTHR;
            if (i < NV4) kreg[j] = src[i];
            else         kreg[j] = make_uint4(0u, 0u, 0u, 0u);
        }
    }

    for (int k = tid; k < BINS; k += NTHR) hist[k] = 0;
    for (int i = tid; i < CAND; i += NTHR) cand[i] = 0ull;
    if (tid < TOPK) ssel[tid] = 0ull;
    if (tid == 0) { scal[0] = 0; scal[1] = 1; }
    __syncthreads();

    const float* lg = logits + ((size_t)b * A_N * C_N) + (c + 1);

    // ---- Pass A: 2048-bin histogram (from registers when USE_WS)
    if (USE_WS) {
        #pragma unroll
        for (int j = 0; j < KPT; ++j) {
            uint4 v = kreg[j];
            if (v.x) atomicAdd(&hist[v.x >> SH], 1u);
            if (v.y) atomicAdd(&hist[v.y >> SH], 1u);
            if (v.z) atomicAdd(&hist[v.z >> SH], 1u);
            if (v.w) atomicAdd(&hist[v.w >> SH], 1u);
        }
    } else {
        for (int a = tid; a < A_N; a += NTHR) {
            float x = lg[(size_t)a * C_N];
            if ((double)x > THR_LOGIT) atomicAdd(&hist[mapf(x) >> SH], 1u);
        }
    }
    __syncthreads();

    // ---- cutoff via wave-level suffix scan (2 barriers total)
    {
        unsigned s = 0;
        #pragma unroll
        for (int k = 0; k < BINS / NTHR; ++k) s += hist[tid * (BINS / NTHR) + k];
        unsigned incl = s;
        int lane = tid & 63;
        #pragma unroll
        for (int off = 1; off < 64; off <<= 1) {
            unsigned v = __shfl_down(incl, off);
            if (lane + off < 64) incl += v;     // incl = sum over lanes >= lane
        }
        if (lane == 0) wtot[tid >> 6] = incl;   // wave total
        __syncthreads();
        unsigned hi = 0;
        #pragma unroll
        for (int w = 0; w < 4; ++w) if (w > (tid >> 6)) hi += wtot[w];
        unsigned excl = hi + (incl - s);        // sum over threads > tid
        if (excl < TOPK && excl + s >= TOPK) {  // unique crossing thread
            unsigned running = excl;
            #pragma unroll
            for (int k = BINS / NTHR - 1; k >= 0; --k) {
                running += hist[tid * (BINS / NTHR) + k];
                if (running >= TOPK) {
                    scal[1] = (int)(((unsigned)(tid * (BINS / NTHR) + k)) << SH);
                    break;
                }
            }
        }
    }
    __syncthreads();
    const unsigned cutoff = (unsigned)scal[1];

    // ---- Pass B: gather candidates >= cutoff from REGISTERS (no re-read)
    if (USE_WS) {
        #pragma unroll
        for (int j = 0; j < KPT; ++j) {
            int i = tid + j * NTHR;
            if (i < NV4) {
                uint4 v = kreg[j];
                int a4 = 4 * i;
                if (v.x >= cutoff && v.x) {
                    int p = atomicAdd(&scal[0], 1);
                    if (p < CAND) cand[p] = ((unsigned long long)v.x << 32) | (unsigned)(~(unsigned)(a4 + 0));
                }
                if (v.y >= cutoff && v.y) {
                    int p = atomicAdd(&scal[0], 1);
                    if (p < CAND) cand[p] = ((unsigned long long)v.y << 32) | (unsigned)(~(unsigned)(a4 + 1));
                }
                if (v.z >= cutoff && v.z) {
                    int p = atomicAdd(&scal[0], 1);
                    if (p < CAND) cand[p] = ((unsigned long long)v.z << 32) | (unsigned)(~(unsigned)(a4 + 2));
                }
                if (v.w >= cutoff && v.w) {
                    int p = atomicAdd(&scal[0], 1);
                    if (p < CAND) cand[p] = ((unsigned long long)v.w << 32) | (unsigned)(~(unsigned)(a4 + 3));
                }
            }
        }
    } else {
        for (int a = tid; a < A_N; a += NTHR) {
            float x = lg[(size_t)a * C_N];
            if ((double)x > THR_LOGIT) {
                unsigned u = mapf(x);
                if (u >= cutoff) {
                    int p = atomicAdd(&scal[0], 1);
                    if (p < CAND) cand[p] = ((unsigned long long)u << 32) | (unsigned)(~(unsigned)a);
                }
            }
        }
    }
    __syncthreads();

    // ---- exact rank via all-pairs over the M gathered (bounded)
    {
        int M = scal[0]; if (M > CAND) M = CAND;
        int Mr = (M + 7) & ~7;
        for (int i = tid; i < Mr; i += NTHR) {
            unsigned long long mykey = cand[i];
            int rank = 0;
            #pragma unroll 8
            for (int j = 0; j < Mr; ++j) rank += (cand[j] > mykey) ? 1 : 0;
            if (mykey != 0ull && rank < TOPK) ssel[rank] = mykey;
        }
    }
    __syncthreads();

    // ---- decode top-100 boxes in f64 (reference op order)
    if (tid < TOPK) {
        unsigned long long key = ssel[tid];
        int valid = (key != 0ull);
        double b0 = 0, b1 = 0, b2 = 0, b3 = 0, area = 0, sc = 0;
        if (valid) {
            int a = (int)(~(unsigned)key);
            float x = unmapf((unsigned)(key >> 32));
            sc = 1.0 / (1.0 + exp(-(double)x));
            float4 r4 = *(const float4*)(boxreg + ((size_t)b * A_N + a) * 4);
            float4 p4 = *(const float4*)(priors + (size_t)a * 4);
            double ty = (double)r4.x / 10.0;
            double tx = (double)r4.y / 10.0;
            double th = (double)r4.z / 5.0;
            double tw = (double)r4.w / 5.0;
            double py = (double)p4.x, px = (double)p4.y;
            double ph = (double)p4.z, pw = (double)p4.w;
            double cy = ty * ph + py;
            double cx = tx * pw + px;
            double hh = exp(th) * ph;
            double ww = exp(tw) * pw;
            b0 = cy - hh / 2.0; b1 = cx - ww / 2.0;
            b2 = cy + hh / 2.0; b3 = cx + ww / 2.0;
            double e0 = b2 - b0; if (e0 < 0.0) e0 = 0.0;
            double e1 = b3 - b1; if (e1 < 0.0) e1 = 0.0;
            area = e0 * e1;
        }
        sb0[tid] = b0; sb1[tid] = b1; sb2[tid] = b2; sb3[tid] = b3;
        sarea[tid] = area; sscore[tid] = sc;
        svalid[tid] = valid;
    }
    __syncthreads();

    // ---- suppression bitmask: thread t -> row i = t>>1, word w = t&1
    if (tid < 2 * TOPK) {
        int i = tid >> 1, w = tid & 1;
        unsigned long long m = 0;
        if (svalid[i]) {
            double i0 = sb0[i], i1 = sb1[i], i2 = sb2[i], i3 = sb3[i], ia = sarea[i];
            int jbase = w * 64;
            int jend = min(jbase + 64, TOPK);
            int jstart = (jbase > i + 1) ? jbase : (i + 1);
            for (int j = jstart; j < jend; ++j) {
                double tl0 = fmax(i0, sb0[j]);
                double tl1 = fmax(i1, sb1[j]);
                double br0 = fmin(i2, sb2[j]);
                double br1 = fmin(i3, sb3[j]);
                double wh0 = br0 - tl0; if (wh0 < 0.0) wh0 = 0.0;
                double wh1 = br1 - tl1; if (wh1 < 0.0) wh1 = 0.0;
                double inter = wh0 * wh1;
                double iou = inter / (((ia + sarea[j]) - inter) + 1e-9);
                if (iou > 0.6) m |= 1ull << (j - jbase);
            }
        }
        supmask[i][w] = m;
    }
    __syncthreads();

    // ---- serial greedy scan over bitmasks
    if (tid == 0) {
        unsigned long long kp0 = ~0ull, kp1 = ~0ull;
        for (int i = 0; i < TOPK; ++i) {
            bool kb = (i < 64) ? ((kp0 >> i) & 1ull) : ((kp1 >> (i - 64)) & 1ull);
            if (kb && svalid[i]) { kp0 &= ~supmask[i][0]; kp1 &= ~supmask[i][1]; }
        }
        keepw[0] = kp0; keepw[1] = kp1;
    }
    __syncthreads();

    // ---- write 5 floats per slot
    if (tid < TOPK) {
        bool kb = (tid < 64) ? ((keepw[0] >> tid) & 1ull)
                             : ((keepw[1] >> (tid - 64)) & 1ull);
        bool kp = kb && (svalid[tid] != 0);
        size_t base = ((size_t)task * TOPK + tid) * 5;
        out[base + 0] = kp ? (float)sb0[tid] : 0.0f;
        out[base + 1] = kp ? (float)sb1[tid] : 0.0f;
        out[base + 2] = kp ? (float)sb2[tid] : 0.0f;
        out[base + 3] = kp ? (float)sb3[tid] : 0.0f;
        out[base + 4] = kp ? (float)sscore[tid] : 0.0f;
    }
}

extern "C" void kernel_launch(void* const* d_in, const int* in_sizes, int n_in,
                              void* d_out, int out_size, void* d_ws, size_t ws_size,
                              hipStream_t stream) {
    const float* logits = (const float*)d_in[0];
    const float* boxreg = (const float*)d_in[1];
    const float* priors = (const float*)d_in[2];
    float* out = (float*)d_out;

    const size_t need = (size_t)B_N * NCLS * A_N * sizeof(unsigned);  // 89.4 MB
    if (ws_size >= need) {
        unsigned* keysw = (unsigned*)d_ws;
        const int NT = (A_N + TA - 1) / TA;
        key_transpose_kernel<<<dim3(B_N * NT), dim3(NTHR), 0, stream>>>(logits, keysw);
        ssd_nms_kernel<true><<<dim3(NTASK), dim3(NTHR), 0, stream>>>(
            logits, keysw, boxreg, priors, out);
    } else {
        ssd_nms_kernel<false><<<dim3(NTASK), dim3(NTHR), 0, stream>>>(
            logits, nullptr, boxreg, priors, out);
    }
}